// Round 1
// baseline (888.249 us; speedup 1.0000x reference)
//
#include <hip/hip_runtime.h>

#define T_SEQ 2048
#define BATCH 4
#define NH 16
#define FDIM 16
#define HDIM 64
#define HIDDEN 1024
#define TOK (BATCH * T_SEQ)      // 8192
#define CH 128                   // our chunk size (math is chunking-invariant)
#define NCHUNK (T_SEQ / CH)      // 16
#define NBH (BATCH * NH)         // 64

// workspace offsets (in floats)
#define Q_OFF   0u               // [TOK, 256]
#define K_OFF   2097152u         // [TOK, 256]
#define V_OFF   4194304u         // [TOK, 1024]
#define OA_OFF  12582912u        // [TOK, 1024]
#define S_OFF   20971520u        // [NBH, NCHUNK, 256, 64]
#define MK_OFF  37748736u        // [NBH, NCHUNK, 256]

// ---------------------------------------------------------------------------
// Generic f32 GEMM: out[m,n] = sum_k A[m,k] * W[n,k]   (A:[M,K], W:[N,K])
// BM=128, BN=64, BK=16, 256 threads, 8x4 register tile per thread.
// ---------------------------------------------------------------------------
__global__ __launch_bounds__(256) void gemm_nt(const float* __restrict__ A,
                                               const float* __restrict__ W,
                                               float* __restrict__ out,
                                               int M, int N, int K) {
  __shared__ float As[16][128];
  __shared__ float Ws[16][64];
  const int tid = threadIdx.x;
  const int m0 = blockIdx.x * 128, n0 = blockIdx.y * 64;
  const int tx = tid & 15, ty = tid >> 4;
  const int ar = tid >> 2, ak = (tid & 3) * 4;
  float acc[8][4];
#pragma unroll
  for (int i = 0; i < 8; ++i)
#pragma unroll
    for (int j = 0; j < 4; ++j) acc[i][j] = 0.f;

  for (int k0 = 0; k0 < K; k0 += 16) {
#pragma unroll
    for (int p = 0; p < 2; ++p) {
      float4 a4 = *(const float4*)&A[(size_t)(m0 + ar + p * 64) * K + k0 + ak];
      As[ak + 0][ar + p * 64] = a4.x;
      As[ak + 1][ar + p * 64] = a4.y;
      As[ak + 2][ar + p * 64] = a4.z;
      As[ak + 3][ar + p * 64] = a4.w;
    }
    {
      float4 w4 = *(const float4*)&W[(size_t)(n0 + ar) * K + k0 + ak];
      Ws[ak + 0][ar] = w4.x;
      Ws[ak + 1][ar] = w4.y;
      Ws[ak + 2][ar] = w4.z;
      Ws[ak + 3][ar] = w4.w;
    }
    __syncthreads();
#pragma unroll
    for (int kk = 0; kk < 16; ++kk) {
      float4 a0 = *(const float4*)&As[kk][ty * 8];
      float4 a1 = *(const float4*)&As[kk][ty * 8 + 4];
      float4 b4 = *(const float4*)&Ws[kk][tx * 4];
      float av[8] = {a0.x, a0.y, a0.z, a0.w, a1.x, a1.y, a1.z, a1.w};
      float bv[4] = {b4.x, b4.y, b4.z, b4.w};
#pragma unroll
      for (int i = 0; i < 8; ++i)
#pragma unroll
        for (int j = 0; j < 4; ++j) acc[i][j] += av[i] * bv[j];
    }
    __syncthreads();
  }
#pragma unroll
  for (int i = 0; i < 8; ++i) {
    float4 r = make_float4(acc[i][0], acc[i][1], acc[i][2], acc[i][3]);
    *(float4*)&out[(size_t)(m0 + ty * 8 + i) * N + n0 + tx * 4] = r;
  }
}

// ---------------------------------------------------------------------------
// LayerNorm over 16 features (biased var, eps 1e-5) -> dst[0..15] (LDS row)
// ---------------------------------------------------------------------------
__device__ __forceinline__ void ln16(const float* __restrict__ src,
                                     const float* __restrict__ gamma,
                                     const float* __restrict__ beta,
                                     float* dst) {
  float x[16];
#pragma unroll
  for (int q = 0; q < 4; ++q) {
    float4 v = *(const float4*)(src + q * 4);
    x[q * 4 + 0] = v.x; x[q * 4 + 1] = v.y;
    x[q * 4 + 2] = v.z; x[q * 4 + 3] = v.w;
  }
  float mu = 0.f;
#pragma unroll
  for (int f = 0; f < 16; ++f) mu += x[f];
  mu *= 0.0625f;
  float var = 0.f;
#pragma unroll
  for (int f = 0; f < 16; ++f) { float d = x[f] - mu; var += d * d; }
  var *= 0.0625f;
  const float rs = rsqrtf(var + 1e-5f);
#pragma unroll
  for (int f = 0; f < 16; ++f) dst[f] = (x[f] - mu) * rs * gamma[f] + beta[f];
}

// ---------------------------------------------------------------------------
// Phase 1: per-chunk raw state S_c[r=(i,j)][v] = sum_c xk_i xk_j * v_v
//          and raw Gram Mk_c[i][j] = sum_c xk_i xk_j   (scales applied later)
// grid: (NCHUNK, NBH), 256 threads
// ---------------------------------------------------------------------------
__global__ __launch_bounds__(256) void k_states(const float* __restrict__ Kp,
                                                const float* __restrict__ Vp,
                                                const float* __restrict__ gamma,
                                                const float* __restrict__ beta,
                                                float* __restrict__ S,
                                                float* __restrict__ Mk) {
  const int c = blockIdx.x, bh = blockIdx.y;
  const int b = bh >> 4, h = bh & 15;
  __shared__ float xk[CH][20];
  __shared__ float vsh[CH][HDIM];
  const int tid = threadIdx.x;

  if (tid < CH) {
    const float* src = Kp + (size_t)(b * T_SEQ + c * CH + tid) * (NH * FDIM) + h * FDIM;
    ln16(src, gamma, beta, &xk[tid][0]);
  }
#pragma unroll
  for (int ii = 0; ii < 8; ++ii) {
    int flat = tid + ii * 256;  // over 2048 float4s
    int s = flat >> 4, q4 = flat & 15;
    *(float4*)&vsh[s][q4 * 4] =
        *(const float4*)&Vp[(size_t)(b * T_SEQ + c * CH + s) * (NH * HDIM) + h * HDIM + q4 * 4];
  }
  __syncthreads();

  {  // Gram matrix
    int i = tid >> 4, j = tid & 15;
    float m = 0.f;
    for (int cc = 0; cc < CH; ++cc) m += xk[cc][i] * xk[cc][j];
    Mk[((size_t)bh * NCHUNK + c) * 256 + tid] = m;
  }

  const int i = tid >> 4, vq = tid & 15;
  float acc[16][4];
#pragma unroll
  for (int rr = 0; rr < 16; ++rr)
#pragma unroll
    for (int j = 0; j < 4; ++j) acc[rr][j] = 0.f;

  for (int cc = 0; cc < CH; ++cc) {
    float xi = xk[cc][i];
    float4 v4 = *(const float4*)&vsh[cc][vq * 4];
#pragma unroll
    for (int rr = 0; rr < 16; ++rr) {
      float kf = xi * xk[cc][rr];
      acc[rr][0] += kf * v4.x;
      acc[rr][1] += kf * v4.y;
      acc[rr][2] += kf * v4.z;
      acc[rr][3] += kf * v4.w;
    }
  }
  float* Sp = S + ((size_t)bh * NCHUNK + c) * (256 * HDIM);
#pragma unroll
  for (int rr = 0; rr < 16; ++rr)
    *(float4*)&Sp[(size_t)(i * 16 + rr) * HDIM + vq * 4] =
        make_float4(acc[rr][0], acc[rr][1], acc[rr][2], acc[rr][3]);
}

// ---------------------------------------------------------------------------
// Phase 2: exclusive prefix over chunks (in place), element-parallel
// ---------------------------------------------------------------------------
__global__ __launch_bounds__(256) void k_prefix_s(float* __restrict__ S) {
  const int bh = blockIdx.y;
  const int e = blockIdx.x * 256 + threadIdx.x;  // < 16384
  size_t base = (size_t)bh * NCHUNK * (256 * HDIM) + e;
  float run = 0.f;
  for (int c = 0; c < NCHUNK; ++c) {
    float v = S[base + (size_t)c * (256 * HDIM)];
    S[base + (size_t)c * (256 * HDIM)] = run;
    run += v;
  }
}

__global__ __launch_bounds__(256) void k_prefix_mk(float* __restrict__ Mk) {
  const int bh = blockIdx.x;
  const int e = threadIdx.x;  // < 256
  size_t base = (size_t)bh * NCHUNK * 256 + e;
  float run = 0.f;
  for (int c = 0; c < NCHUNK; ++c) {
    float v = Mk[base + (size_t)c * 256];
    Mk[base + (size_t)c * 256] = run;
    run += v;
  }
}

// ---------------------------------------------------------------------------
// Phase 3: per-chunk output.
//   o_t = sum_{s<=t,in-chunk} (xq_t.xk_s)^2/16 * v_s  +  (1/16) qq^T P_c
//   z_t = same scalar sums; out = o / (z + 1e-10)
// grid: (NCHUNK, NBH), 256 threads: thread = (token t, half g of HD)
// ---------------------------------------------------------------------------
__global__ __launch_bounds__(256) void k_attn_out(const float* __restrict__ Qp,
                                                  const float* __restrict__ Kp,
                                                  const float* __restrict__ Vp,
                                                  const float* __restrict__ gamma,
                                                  const float* __restrict__ beta,
                                                  const float* __restrict__ S,
                                                  const float* __restrict__ Mk,
                                                  float* __restrict__ O) {
  const int c = blockIdx.x, bh = blockIdx.y;
  const int b = bh >> 4, h = bh & 15;
  __shared__ float xq[CH][20];
  __shared__ float xk[CH][20];
  __shared__ float vsh[CH][HDIM];
  __shared__ float Psh[64][HDIM];
  __shared__ float mksh[256];
  const int tid = threadIdx.x;

  if (tid < CH) {
    const float* src = Qp + (size_t)(b * T_SEQ + c * CH + tid) * (NH * FDIM) + h * FDIM;
    ln16(src, gamma, beta, &xq[tid][0]);
  } else {
    const int tt = tid - CH;
    const float* src = Kp + (size_t)(b * T_SEQ + c * CH + tt) * (NH * FDIM) + h * FDIM;
    ln16(src, gamma, beta, &xk[tt][0]);
  }
#pragma unroll
  for (int ii = 0; ii < 8; ++ii) {
    int flat = tid + ii * 256;
    int s = flat >> 4, q4 = flat & 15;
    *(float4*)&vsh[s][q4 * 4] =
        *(const float4*)&Vp[(size_t)(b * T_SEQ + c * CH + s) * (NH * HDIM) + h * HDIM + q4 * 4];
  }
  mksh[tid] = Mk[((size_t)bh * NCHUNK + c) * 256 + tid];
  __syncthreads();

  const int t = tid >> 1, g2 = tid & 1;
  float xqr[16];
#pragma unroll
  for (int f = 0; f < 16; ++f) xqr[f] = xq[t][f];

  float o[32];
#pragma unroll
  for (int j = 0; j < 32; ++j) o[j] = 0.f;
  float z = 0.f;

  // intra-chunk (causal, diagonal included)
  for (int s = 0; s <= t; ++s) {
    float4 k0 = *(const float4*)&xk[s][0];
    float4 k1 = *(const float4*)&xk[s][4];
    float4 k2 = *(const float4*)&xk[s][8];
    float4 k3 = *(const float4*)&xk[s][12];
    float d = xqr[0] * k0.x + xqr[1] * k0.y + xqr[2] * k0.z + xqr[3] * k0.w +
              xqr[4] * k1.x + xqr[5] * k1.y + xqr[6] * k1.z + xqr[7] * k1.w +
              xqr[8] * k2.x + xqr[9] * k2.y + xqr[10] * k2.z + xqr[11] * k2.w +
              xqr[12] * k3.x + xqr[13] * k3.y + xqr[14] * k3.z + xqr[15] * k3.w;
    float a = d * d * 0.0625f;
    z += a;
#pragma unroll
    for (int j = 0; j < 8; ++j) {
      float4 v4 = *(const float4*)&vsh[s][g2 * 32 + j * 4];
      o[j * 4 + 0] += a * v4.x;
      o[j * 4 + 1] += a * v4.y;
      o[j * 4 + 2] += a * v4.z;
      o[j * 4 + 3] += a * v4.w;
    }
  }

  // inter-chunk via prefix state
  const float* Pp = S + ((size_t)bh * NCHUNK + c) * (256 * HDIM);
#pragma unroll
  for (int tile = 0; tile < 4; ++tile) {
    __syncthreads();
#pragma unroll
    for (int ii = 0; ii < 4; ++ii) {
      int flat = tid + ii * 256;  // over 1024 float4s
      int r = flat >> 4, q4 = flat & 15;
      *(float4*)&Psh[r][q4 * 4] =
          *(const float4*)&Pp[(size_t)(tile * 64 + r) * HDIM + q4 * 4];
    }
    __syncthreads();
#pragma unroll
    for (int rr = 0; rr < 64; ++rr) {
      float qq = xqr[tile * 4 + (rr >> 4)] * xqr[rr & 15] * 0.0625f;
#pragma unroll
      for (int j = 0; j < 8; ++j) {
        float4 p4 = *(const float4*)&Psh[rr][g2 * 32 + j * 4];
        o[j * 4 + 0] += qq * p4.x;
        o[j * 4 + 1] += qq * p4.y;
        o[j * 4 + 2] += qq * p4.z;
        o[j * 4 + 3] += qq * p4.w;
      }
    }
  }

  // z inter via prefix Gram
  float zi = 0.f;
#pragma unroll
  for (int i = 0; i < 16; ++i)
#pragma unroll
    for (int j = 0; j < 16; ++j) zi += xqr[i] * xqr[j] * mksh[i * 16 + j];
  z += zi * 0.0625f;

  const float inv = 1.0f / (z + 1e-10f);
  float* op = O + (size_t)(b * T_SEQ + c * CH + t) * (NH * HDIM) + h * HDIM + g2 * 32;
#pragma unroll
  for (int j = 0; j < 8; ++j)
    *(float4*)&op[j * 4] = make_float4(o[j * 4 + 0] * inv, o[j * 4 + 1] * inv,
                                       o[j * 4 + 2] * inv, o[j * 4 + 3] * inv);
}

// ---------------------------------------------------------------------------
extern "C" void kernel_launch(void* const* d_in, const int* in_sizes, int n_in,
                              void* d_out, int out_size, void* d_ws, size_t ws_size,
                              hipStream_t stream) {
  const float* hs    = (const float*)d_in[0];
  const float* Wq    = (const float*)d_in[1];
  const float* Wk    = (const float*)d_in[2];
  const float* Wv    = (const float*)d_in[3];
  const float* Wo    = (const float*)d_in[4];
  const float* gamma = (const float*)d_in[5];
  const float* beta  = (const float*)d_in[6];
  float* out = (float*)d_out;
  float* ws  = (float*)d_ws;

  float* Q  = ws + Q_OFF;
  float* Kf = ws + K_OFF;
  float* V  = ws + V_OFF;
  float* OA = ws + OA_OFF;
  float* S  = ws + S_OFF;
  float* Mk = ws + MK_OFF;

  dim3 blk(256);
  gemm_nt<<<dim3(64, 4), blk, 0, stream>>>(hs, Wq, Q, TOK, 256, HIDDEN);
  gemm_nt<<<dim3(64, 4), blk, 0, stream>>>(hs, Wk, Kf, TOK, 256, HIDDEN);
  gemm_nt<<<dim3(64, 16), blk, 0, stream>>>(hs, Wv, V, TOK, 1024, HIDDEN);
  k_states<<<dim3(NCHUNK, NBH), blk, 0, stream>>>(Kf, V, gamma, beta, S, Mk);
  k_prefix_s<<<dim3(64, NBH), blk, 0, stream>>>(S);
  k_prefix_mk<<<NBH, blk, 0, stream>>>(Mk);
  k_attn_out<<<dim3(NCHUNK, NBH), blk, 0, stream>>>(Q, Kf, V, gamma, beta, S, Mk, OA);
  gemm_nt<<<dim3(64, 16), blk, 0, stream>>>(OA, Wo, out, TOK, 1024, HIDDEN);
}

// Round 2
// 301.529 us; speedup vs baseline: 2.9458x; 2.9458x over previous
//
#include <hip/hip_runtime.h>

#define T_SEQ 2048
#define BATCH 4
#define NH 16
#define FDIM 16
#define HDIM 64
#define HIDDEN 1024
#define TOK (BATCH * T_SEQ)      // 8192
#define CH 128
#define NCHUNK (T_SEQ / CH)      // 16
#define NBH (BATCH * NH)         // 64

// workspace offsets (float32 units)
#define QK_OFF  0u               // f32 [TOK, 512]  (Q cols 0..255, K cols 256..511)
#define V_OFF   4194304u         // bf16 [TOK, 1024] (as ushort)
#define S_OFF   8388608u         // f32 [NBH, NCHUNK, 256, 64]
#define MK_OFF  25165824u        // f32 [NBH, NCHUNK, 256]
#define HSB_OFF 25427968u        // bf16 [TOK, 1024]
#define OAB_OFF 29622272u        // bf16 [TOK, 1024]
#define WQK_OFF 33816576u        // bf16 [512, 1024]
#define WV_OFF  34078720u        // bf16 [1024, 1024]
#define WO_OFF  34603008u        // bf16 [1024, 1024]

typedef float f32x4 __attribute__((ext_vector_type(4)));
typedef short bf16x8 __attribute__((ext_vector_type(8)));
typedef unsigned short ushort8 __attribute__((ext_vector_type(8)));
typedef unsigned int u32;

__device__ __forceinline__ unsigned short f2b(float f) {
  union { float f; unsigned u; } v; v.f = f;
  unsigned r = (v.u + 0x7FFFu + ((v.u >> 16) & 1u)) >> 16;
  return (unsigned short)r;
}
__device__ __forceinline__ float b2f(unsigned short h) {
  union { unsigned u; float f; } v; v.u = ((unsigned)h) << 16; return v.f;
}

__device__ __forceinline__ void gload_lds16(const void* g, void* l) {
  __builtin_amdgcn_global_load_lds(
      (const __attribute__((address_space(1))) u32*)g,
      (__attribute__((address_space(3))) u32*)l, 16, 0, 0);
}

// ---------------------------------------------------------------------------
// f32 -> bf16 convert, 8 elements/thread
// ---------------------------------------------------------------------------
__global__ __launch_bounds__(256) void f32_to_bf16(const float* __restrict__ src,
                                                   unsigned short* __restrict__ dst,
                                                   int n8) {
  int i = blockIdx.x * 256 + threadIdx.x;
  if (i >= n8) return;
  const float4* s = (const float4*)src;
  float4 v0 = s[i * 2], v1 = s[i * 2 + 1];
  ushort8 o;
  o[0] = f2b(v0.x); o[1] = f2b(v0.y); o[2] = f2b(v0.z); o[3] = f2b(v0.w);
  o[4] = f2b(v1.x); o[5] = f2b(v1.y); o[6] = f2b(v1.z); o[7] = f2b(v1.w);
  *(ushort8*)&dst[i * 8] = o;
}

// ---------------------------------------------------------------------------
// bf16 MFMA GEMM (m97 structure): C[m,n] = sum_k A[m,k] * W[n,k]
// A:[M,K] bf16, W:[N,K] bf16. 128x128 tile, BK=64, 4 waves, 16x16x32 MFMA.
// OUT_BF16: store C as bf16 (ushort) else f32.
// ---------------------------------------------------------------------------
template <bool OUT_BF16>
__global__ __launch_bounds__(256) void gemm_mfma(const unsigned short* __restrict__ A,
                                                 const unsigned short* __restrict__ W,
                                                 void* __restrict__ Cv,
                                                 int N, int K) {
  __shared__ unsigned short Asl[128][64];
  __shared__ unsigned short Bsl[128][64];
  const int tid = threadIdx.x;
  const int lane = tid & 63, wid = tid >> 6;
  const int wr = wid >> 1, wc = wid & 1;
  const int m0 = blockIdx.x * 128, n0 = blockIdx.y * 128;

  f32x4 acc[4][4];
#pragma unroll
  for (int m = 0; m < 4; ++m)
#pragma unroll
    for (int n = 0; n < 4; ++n) acc[m][n] = (f32x4){0.f, 0.f, 0.f, 0.f};

  const int srow = (lane >> 3);          // 0..7 within 8-row group
  const int skoff = (lane & 7) * 8;      // bf16 k offset within row

  for (int k0 = 0; k0 < K; k0 += 64) {
#pragma unroll
    for (int i = 0; i < 4; ++i) {
      int ra = wid * 32 + i * 8;
      gload_lds16(&A[(size_t)(m0 + ra + srow) * K + k0 + skoff], &Asl[ra][0]);
      gload_lds16(&W[(size_t)(n0 + ra + srow) * K + k0 + skoff], &Bsl[ra][0]);
    }
    __syncthreads();
#pragma unroll
    for (int kk = 0; kk < 2; ++kk) {
      bf16x8 af[4], bf_[4];
#pragma unroll
      for (int m = 0; m < 4; ++m)
        af[m] = *(const bf16x8*)&Asl[wr * 64 + m * 16 + (lane & 15)][kk * 32 + (lane >> 4) * 8];
#pragma unroll
      for (int n = 0; n < 4; ++n)
        bf_[n] = *(const bf16x8*)&Bsl[wc * 64 + n * 16 + (lane & 15)][kk * 32 + (lane >> 4) * 8];
#pragma unroll
      for (int m = 0; m < 4; ++m)
#pragma unroll
        for (int n = 0; n < 4; ++n)
          acc[m][n] = __builtin_amdgcn_mfma_f32_16x16x32_bf16(af[m], bf_[n], acc[m][n], 0, 0, 0);
    }
    __syncthreads();
  }

  // epilogue: C/D layout col=lane&15, row=(lane>>4)*4+j
#pragma unroll
  for (int m = 0; m < 4; ++m)
#pragma unroll
    for (int n = 0; n < 4; ++n) {
      int col = n0 + wc * 64 + n * 16 + (lane & 15);
#pragma unroll
      for (int j = 0; j < 4; ++j) {
        int row = m0 + wr * 64 + m * 16 + (lane >> 4) * 4 + j;
        if (OUT_BF16)
          ((unsigned short*)Cv)[(size_t)row * N + col] = f2b(acc[m][n][j]);
        else
          ((float*)Cv)[(size_t)row * N + col] = acc[m][n][j];
      }
    }
}

// ---------------------------------------------------------------------------
// LayerNorm over 16 features
// ---------------------------------------------------------------------------
__device__ __forceinline__ void ln16(const float* __restrict__ src,
                                     const float* __restrict__ gamma,
                                     const float* __restrict__ beta,
                                     float* dst) {
  float x[16];
#pragma unroll
  for (int q = 0; q < 4; ++q) {
    float4 v = *(const float4*)(src + q * 4);
    x[q * 4 + 0] = v.x; x[q * 4 + 1] = v.y;
    x[q * 4 + 2] = v.z; x[q * 4 + 3] = v.w;
  }
  float mu = 0.f;
#pragma unroll
  for (int f = 0; f < 16; ++f) mu += x[f];
  mu *= 0.0625f;
  float var = 0.f;
#pragma unroll
  for (int f = 0; f < 16; ++f) { float d = x[f] - mu; var += d * d; }
  var *= 0.0625f;
  const float rs = rsqrtf(var + 1e-5f);
#pragma unroll
  for (int f = 0; f < 16; ++f) dst[f] = (x[f] - mu) * rs * gamma[f] + beta[f];
}

// ---------------------------------------------------------------------------
// Phase 1: per-chunk raw state + raw Gram
// ---------------------------------------------------------------------------
__global__ __launch_bounds__(256) void k_states(const float* __restrict__ QK,
                                                const unsigned short* __restrict__ Vb,
                                                const float* __restrict__ gamma,
                                                const float* __restrict__ beta,
                                                float* __restrict__ S,
                                                float* __restrict__ Mk) {
  const int c = blockIdx.x, bh = blockIdx.y;
  const int b = bh >> 4, h = bh & 15;
  __shared__ float xk[CH][20];
  __shared__ float vsh[CH][HDIM];
  const int tid = threadIdx.x;

  if (tid < CH) {
    const float* src = QK + (size_t)(b * T_SEQ + c * CH + tid) * 512 + 256 + h * FDIM;
    ln16(src, gamma, beta, &xk[tid][0]);
  }
#pragma unroll
  for (int ii = 0; ii < 4; ++ii) {
    int flat = tid + ii * 256;  // over 1024 8-elt chunks
    int s = flat >> 3, q8 = flat & 7;
    ushort8 v8 = *(const ushort8*)&Vb[(size_t)(b * T_SEQ + c * CH + s) * (NH * HDIM) + h * HDIM + q8 * 8];
    *(float4*)&vsh[s][q8 * 8 + 0] = make_float4(b2f(v8[0]), b2f(v8[1]), b2f(v8[2]), b2f(v8[3]));
    *(float4*)&vsh[s][q8 * 8 + 4] = make_float4(b2f(v8[4]), b2f(v8[5]), b2f(v8[6]), b2f(v8[7]));
  }
  __syncthreads();

  {  // Gram matrix
    int i = tid >> 4, j = tid & 15;
    float m = 0.f;
    for (int cc = 0; cc < CH; ++cc) m += xk[cc][i] * xk[cc][j];
    Mk[((size_t)bh * NCHUNK + c) * 256 + tid] = m;
  }

  const int i = tid >> 4, vq = tid & 15;
  float acc[16][4];
#pragma unroll
  for (int rr = 0; rr < 16; ++rr)
#pragma unroll
    for (int j = 0; j < 4; ++j) acc[rr][j] = 0.f;

  for (int cc = 0; cc < CH; ++cc) {
    float xi = xk[cc][i];
    float4 v4 = *(const float4*)&vsh[cc][vq * 4];
#pragma unroll
    for (int rr = 0; rr < 16; ++rr) {
      float kf = xi * xk[cc][rr];
      acc[rr][0] += kf * v4.x;
      acc[rr][1] += kf * v4.y;
      acc[rr][2] += kf * v4.z;
      acc[rr][3] += kf * v4.w;
    }
  }
  float* Sp = S + ((size_t)bh * NCHUNK + c) * (256 * HDIM);
#pragma unroll
  for (int rr = 0; rr < 16; ++rr)
    *(float4*)&Sp[(size_t)(i * 16 + rr) * HDIM + vq * 4] =
        make_float4(acc[rr][0], acc[rr][1], acc[rr][2], acc[rr][3]);
}

// ---------------------------------------------------------------------------
// Phase 2: exclusive prefix over chunks
// ---------------------------------------------------------------------------
__global__ __launch_bounds__(256) void k_prefix_s(float* __restrict__ S) {
  const int bh = blockIdx.y;
  const int e = blockIdx.x * 256 + threadIdx.x;
  size_t base = (size_t)bh * NCHUNK * (256 * HDIM) + e;
  float run = 0.f;
  for (int c = 0; c < NCHUNK; ++c) {
    float v = S[base + (size_t)c * (256 * HDIM)];
    S[base + (size_t)c * (256 * HDIM)] = run;
    run += v;
  }
}

__global__ __launch_bounds__(256) void k_prefix_mk(float* __restrict__ Mk) {
  const int bh = blockIdx.x;
  const int e = threadIdx.x;
  size_t base = (size_t)bh * NCHUNK * 256 + e;
  float run = 0.f;
  for (int c = 0; c < NCHUNK; ++c) {
    float v = Mk[base + (size_t)c * 256];
    Mk[base + (size_t)c * 256] = run;
    run += v;
  }
}

// ---------------------------------------------------------------------------
// Phase 3: per-chunk output -> OA (bf16)
// ---------------------------------------------------------------------------
__global__ __launch_bounds__(256) void k_attn_out(const float* __restrict__ QK,
                                                  const unsigned short* __restrict__ Vb,
                                                  const float* __restrict__ gamma,
                                                  const float* __restrict__ beta,
                                                  const float* __restrict__ S,
                                                  const float* __restrict__ Mk,
                                                  unsigned short* __restrict__ OAB) {
  const int c = blockIdx.x, bh = blockIdx.y;
  const int b = bh >> 4, h = bh & 15;
  __shared__ float xq[CH][20];
  __shared__ float xk[CH][20];
  __shared__ float vsh[CH][HDIM];
  __shared__ float Psh[64][HDIM];
  __shared__ float mksh[256];
  const int tid = threadIdx.x;

  if (tid < CH) {
    const float* src = QK + (size_t)(b * T_SEQ + c * CH + tid) * 512 + h * FDIM;
    ln16(src, gamma, beta, &xq[tid][0]);
  } else {
    const int tt = tid - CH;
    const float* src = QK + (size_t)(b * T_SEQ + c * CH + tt) * 512 + 256 + h * FDIM;
    ln16(src, gamma, beta, &xk[tt][0]);
  }
#pragma unroll
  for (int ii = 0; ii < 4; ++ii) {
    int flat = tid + ii * 256;
    int s = flat >> 3, q8 = flat & 7;
    ushort8 v8 = *(const ushort8*)&Vb[(size_t)(b * T_SEQ + c * CH + s) * (NH * HDIM) + h * HDIM + q8 * 8];
    *(float4*)&vsh[s][q8 * 8 + 0] = make_float4(b2f(v8[0]), b2f(v8[1]), b2f(v8[2]), b2f(v8[3]));
    *(float4*)&vsh[s][q8 * 8 + 4] = make_float4(b2f(v8[4]), b2f(v8[5]), b2f(v8[6]), b2f(v8[7]));
  }
  mksh[tid] = Mk[((size_t)bh * NCHUNK + c) * 256 + tid];
  __syncthreads();

  const int t = tid >> 1, g2 = tid & 1;
  float xqr[16];
#pragma unroll
  for (int f = 0; f < 16; ++f) xqr[f] = xq[t][f];

  float o[32];
#pragma unroll
  for (int j = 0; j < 32; ++j) o[j] = 0.f;
  float z = 0.f;

  // intra-chunk (causal)
  for (int s = 0; s <= t; ++s) {
    float4 k0 = *(const float4*)&xk[s][0];
    float4 k1 = *(const float4*)&xk[s][4];
    float4 k2 = *(const float4*)&xk[s][8];
    float4 k3 = *(const float4*)&xk[s][12];
    float d = xqr[0] * k0.x + xqr[1] * k0.y + xqr[2] * k0.z + xqr[3] * k0.w +
              xqr[4] * k1.x + xqr[5] * k1.y + xqr[6] * k1.z + xqr[7] * k1.w +
              xqr[8] * k2.x + xqr[9] * k2.y + xqr[10] * k2.z + xqr[11] * k2.w +
              xqr[12] * k3.x + xqr[13] * k3.y + xqr[14] * k3.z + xqr[15] * k3.w;
    float a = d * d * 0.0625f;
    z += a;
#pragma unroll
    for (int j = 0; j < 8; ++j) {
      float4 v4 = *(const float4*)&vsh[s][g2 * 32 + j * 4];
      o[j * 4 + 0] += a * v4.x;
      o[j * 4 + 1] += a * v4.y;
      o[j * 4 + 2] += a * v4.z;
      o[j * 4 + 3] += a * v4.w;
    }
  }

  // inter-chunk via prefix state
  const float* Pp = S + ((size_t)bh * NCHUNK + c) * (256 * HDIM);
#pragma unroll
  for (int tile = 0; tile < 4; ++tile) {
    __syncthreads();
#pragma unroll
    for (int ii = 0; ii < 4; ++ii) {
      int flat = tid + ii * 256;
      int r = flat >> 4, q4 = flat & 15;
      *(float4*)&Psh[r][q4 * 4] =
          *(const float4*)&Pp[(size_t)(tile * 64 + r) * HDIM + q4 * 4];
    }
    __syncthreads();
#pragma unroll
    for (int rr = 0; rr < 64; ++rr) {
      float qq = xqr[tile * 4 + (rr >> 4)] * xqr[rr & 15] * 0.0625f;
#pragma unroll
      for (int j = 0; j < 8; ++j) {
        float4 p4 = *(const float4*)&Psh[rr][g2 * 32 + j * 4];
        o[j * 4 + 0] += qq * p4.x;
        o[j * 4 + 1] += qq * p4.y;
        o[j * 4 + 2] += qq * p4.z;
        o[j * 4 + 3] += qq * p4.w;
      }
    }
  }

  // z inter via prefix Gram
  float zi = 0.f;
#pragma unroll
  for (int i = 0; i < 16; ++i)
#pragma unroll
    for (int j = 0; j < 16; ++j) zi += xqr[i] * xqr[j] * mksh[i * 16 + j];
  z += zi * 0.0625f;

  const float inv = 1.0f / (z + 1e-10f);
  unsigned short* op = OAB + (size_t)(b * T_SEQ + c * CH + t) * (NH * HDIM) + h * HDIM + g2 * 32;
#pragma unroll
  for (int q = 0; q < 4; ++q) {
    ushort8 r;
#pragma unroll
    for (int j = 0; j < 8; ++j) r[j] = f2b(o[q * 8 + j] * inv);
    *(ushort8*)&op[q * 8] = r;
  }
}

// ---------------------------------------------------------------------------
extern "C" void kernel_launch(void* const* d_in, const int* in_sizes, int n_in,
                              void* d_out, int out_size, void* d_ws, size_t ws_size,
                              hipStream_t stream) {
  const float* hs    = (const float*)d_in[0];
  const float* Wq    = (const float*)d_in[1];
  const float* Wk    = (const float*)d_in[2];
  const float* Wv    = (const float*)d_in[3];
  const float* Wo    = (const float*)d_in[4];
  const float* gamma = (const float*)d_in[5];
  const float* beta  = (const float*)d_in[6];
  float* out = (float*)d_out;
  float* ws  = (float*)d_ws;

  float* QK = ws + QK_OFF;
  unsigned short* Vb  = (unsigned short*)(ws + V_OFF);
  float* S  = ws + S_OFF;
  float* Mk = ws + MK_OFF;
  unsigned short* HSB = (unsigned short*)(ws + HSB_OFF);
  unsigned short* OAB = (unsigned short*)(ws + OAB_OFF);
  unsigned short* WQKB = (unsigned short*)(ws + WQK_OFF);
  unsigned short* WVB  = (unsigned short*)(ws + WV_OFF);
  unsigned short* WOB  = (unsigned short*)(ws + WO_OFF);

  dim3 blk(256);
  f32_to_bf16<<<4096, blk, 0, stream>>>(hs, HSB, TOK * HIDDEN / 8);
  f32_to_bf16<<<128, blk, 0, stream>>>(Wq, WQKB, 256 * HIDDEN / 8);
  f32_to_bf16<<<128, blk, 0, stream>>>(Wk, WQKB + 256 * HIDDEN, 256 * HIDDEN / 8);
  f32_to_bf16<<<512, blk, 0, stream>>>(Wv, WVB, 1024 * HIDDEN / 8);
  f32_to_bf16<<<512, blk, 0, stream>>>(Wo, WOB, 1024 * HIDDEN / 8);

  gemm_mfma<false><<<dim3(64, 4), blk, 0, stream>>>(HSB, WQKB, QK, 512, HIDDEN);
  gemm_mfma<true ><<<dim3(64, 8), blk, 0, stream>>>(HSB, WVB, Vb, 1024, HIDDEN);

  k_states<<<dim3(NCHUNK, NBH), blk, 0, stream>>>(QK, Vb, gamma, beta, S, Mk);
  k_prefix_s<<<dim3(64, NBH), blk, 0, stream>>>(S);
  k_prefix_mk<<<NBH, blk, 0, stream>>>(Mk);
  k_attn_out<<<dim3(NCHUNK, NBH), blk, 0, stream>>>(QK, Vb, gamma, beta, S, Mk, OAB);

  gemm_mfma<false><<<dim3(64, 8), blk, 0, stream>>>(OAB, WOB, out, 1024, HIDDEN);
}

// Round 3
// 163.563 us; speedup vs baseline: 5.4306x; 1.8435x over previous
//
#include <hip/hip_runtime.h>

#define T_SEQ 2048
#define BATCH 4
#define NH 16
#define FDIM 16
#define HDIM 64
#define HIDDEN 1024
#define TOK (BATCH * T_SEQ)      // 8192
#define CH 128
#define NCHUNK (T_SEQ / CH)      // 16
#define NBH (BATCH * NH)         // 64

// workspace offsets (float32 units)
#define QK_OFF   0u              // f32 [TOK, 512]  (Q cols 0..255, K cols 256..511)
#define VT_OFF   4194304u        // bf16 [NBH][64 v][2048 t]
#define SRAW_OFF 8388608u        // bf16 [NBH][NCHUNK][64 n][256 r]
#define SPRE_OFF 16777216u       // bf16 same layout (exclusive prefix)
#define MK_OFF   25165824u       // f32 [NBH][NCHUNK][256]
#define HSB_OFF  25427968u       // bf16 [TOK,1024]
#define OAB_OFF  29622272u       // bf16 [TOK,1024]
#define WQK_OFF  33816576u       // bf16 [512,1024]
#define WV_OFF   34078720u       // bf16 [1024,1024]
#define WO_OFF   34603008u       // bf16 [1024,1024]

typedef float f32x4 __attribute__((ext_vector_type(4)));
typedef short bf16x8 __attribute__((ext_vector_type(8)));
typedef unsigned short us8 __attribute__((ext_vector_type(8)));
typedef unsigned short us4 __attribute__((ext_vector_type(4)));
typedef unsigned int u32;

__device__ __forceinline__ unsigned short f2b(float f) {
  union { float f; unsigned u; } v; v.f = f;
  unsigned r = (v.u + 0x7FFFu + ((v.u >> 16) & 1u)) >> 16;
  return (unsigned short)r;
}
__device__ __forceinline__ float b2f(unsigned short h) {
  union { unsigned u; float f; } v; v.u = ((unsigned)h) << 16; return v.f;
}

__device__ __forceinline__ void gload_lds16(const void* g, void* l) {
  __builtin_amdgcn_global_load_lds(
      (const __attribute__((address_space(1))) u32*)g,
      (__attribute__((address_space(3))) u32*)l, 16, 0, 0);
}

// ---------------------------------------------------------------------------
__global__ __launch_bounds__(256) void f32_to_bf16(const float* __restrict__ src,
                                                   unsigned short* __restrict__ dst,
                                                   int n8) {
  int i = blockIdx.x * 256 + threadIdx.x;
  if (i >= n8) return;
  const float4* s = (const float4*)src;
  float4 v0 = s[i * 2], v1 = s[i * 2 + 1];
  us8 o;
  o[0] = f2b(v0.x); o[1] = f2b(v0.y); o[2] = f2b(v0.z); o[3] = f2b(v0.w);
  o[4] = f2b(v1.x); o[5] = f2b(v1.y); o[6] = f2b(v1.z); o[7] = f2b(v1.w);
  *(us8*)&dst[i * 8] = o;
}

// ---------------------------------------------------------------------------
// bf16 MFMA GEMM: C[m,n] = sum_k A[m,k]*W[n,k]. 128x128 tile, BK=64, 4 waves.
// MODE 0: f32 row-major  MODE 1: bf16 row-major  MODE 2: bf16 V-transposed
// ---------------------------------------------------------------------------
template <int MODE>
__global__ __launch_bounds__(256) void gemm_mfma(const unsigned short* __restrict__ A,
                                                 const unsigned short* __restrict__ W,
                                                 void* __restrict__ Cv,
                                                 int N, int K) {
  __shared__ unsigned short Asl[128][64];
  __shared__ unsigned short Bsl[128][64];
  const int tid = threadIdx.x;
  const int lane = tid & 63, wid = tid >> 6;
  const int wr = wid >> 1, wc = wid & 1;
  const int m0 = blockIdx.x * 128, n0 = blockIdx.y * 128;

  f32x4 acc[4][4];
#pragma unroll
  for (int m = 0; m < 4; ++m)
#pragma unroll
    for (int n = 0; n < 4; ++n) acc[m][n] = (f32x4){0.f, 0.f, 0.f, 0.f};

  const int srow = (lane >> 3);
  const int skoff = (lane & 7) * 8;

  for (int k0 = 0; k0 < K; k0 += 64) {
#pragma unroll
    for (int i = 0; i < 4; ++i) {
      int ra = wid * 32 + i * 8;
      gload_lds16(&A[(size_t)(m0 + ra + srow) * K + k0 + skoff], &Asl[ra][0]);
      gload_lds16(&W[(size_t)(n0 + ra + srow) * K + k0 + skoff], &Bsl[ra][0]);
    }
    __syncthreads();
#pragma unroll
    for (int kk = 0; kk < 2; ++kk) {
      bf16x8 af[4], bf_[4];
#pragma unroll
      for (int m = 0; m < 4; ++m)
        af[m] = *(const bf16x8*)&Asl[wr * 64 + m * 16 + (lane & 15)][kk * 32 + (lane >> 4) * 8];
#pragma unroll
      for (int n = 0; n < 4; ++n)
        bf_[n] = *(const bf16x8*)&Bsl[wc * 64 + n * 16 + (lane & 15)][kk * 32 + (lane >> 4) * 8];
#pragma unroll
      for (int m = 0; m < 4; ++m)
#pragma unroll
        for (int n = 0; n < 4; ++n)
          acc[m][n] = __builtin_amdgcn_mfma_f32_16x16x32_bf16(af[m], bf_[n], acc[m][n], 0, 0, 0);
    }
    __syncthreads();
  }

#pragma unroll
  for (int m = 0; m < 4; ++m)
#pragma unroll
    for (int n = 0; n < 4; ++n) {
      int col = n0 + wc * 64 + n * 16 + (lane & 15);
      int row0 = m0 + wr * 64 + m * 16 + (lane >> 4) * 4;
      if (MODE == 2) {
        // V_T[bh][v][t]: b=row>>11, tl=row&2047, h=col>>6, v=col&63
        int b = row0 >> 11, tl = row0 & 2047;
        int hh = col >> 6, v = col & 63;
        us4 pk;
#pragma unroll
        for (int j = 0; j < 4; ++j) pk[j] = f2b(acc[m][n][j]);
        *(us4*)&((unsigned short*)Cv)[(((size_t)(b * 16 + hh) * 64 + v) << 11) + tl] = pk;
      } else {
#pragma unroll
        for (int j = 0; j < 4; ++j) {
          int row = row0 + j;
          if (MODE == 1)
            ((unsigned short*)Cv)[(size_t)row * N + col] = f2b(acc[m][n][j]);
          else
            ((float*)Cv)[(size_t)row * N + col] = acc[m][n][j];
        }
      }
    }
}

// ---------------------------------------------------------------------------
__device__ __forceinline__ void ln16(const float* __restrict__ src,
                                     const float* __restrict__ gamma,
                                     const float* __restrict__ beta,
                                     float* dst) {
  float x[16];
#pragma unroll
  for (int q = 0; q < 4; ++q) {
    float4 v = *(const float4*)(src + q * 4);
    x[q * 4 + 0] = v.x; x[q * 4 + 1] = v.y;
    x[q * 4 + 2] = v.z; x[q * 4 + 3] = v.w;
  }
  float mu = 0.f;
#pragma unroll
  for (int f = 0; f < 16; ++f) mu += x[f];
  mu *= 0.0625f;
  float var = 0.f;
#pragma unroll
  for (int f = 0; f < 16; ++f) { float d = x[f] - mu; var += d * d; }
  var *= 0.0625f;
  const float rs = rsqrtf(var + 1e-5f);
#pragma unroll
  for (int f = 0; f < 16; ++f) dst[f] = (x[f] - mu) * rs * gamma[f] + beta[f];
}

// ---------------------------------------------------------------------------
// Phase 1 (MFMA): S_raw_T[n][r] = sum_s kf[s][r] * V[s][n];  Mk gram (f32).
// A-frag built on the fly: kf[s][r]=xk[s][i]*xk[s][j], r=i*16+j (raw scale).
// ---------------------------------------------------------------------------
__global__ __launch_bounds__(256) void k_states(const float* __restrict__ QK,
                                                const unsigned short* __restrict__ VTg,
                                                const float* __restrict__ gamma,
                                                const float* __restrict__ beta,
                                                unsigned short* __restrict__ Sraw,
                                                float* __restrict__ Mk) {
  const int c = blockIdx.x, bh = blockIdx.y;
  const int b = bh >> 4, h = bh & 15;
  __shared__ float XKT[16][140];           // [feature][token], padded
  __shared__ unsigned short VT[64][152];   // [v][token], padded
  const int tid = threadIdx.x;
  const int lane = tid & 63, wid = tid >> 6;
  const int ln = lane & 15, lg = lane >> 4;

  if (tid < 128) {
    float xr[16];
    ln16(QK + (size_t)(b * T_SEQ + c * CH + tid) * 512 + 256 + h * FDIM, gamma, beta, xr);
#pragma unroll
    for (int f = 0; f < 16; ++f) XKT[f][tid] = xr[f];
  }
#pragma unroll
  for (int it = 0; it < 4; ++it) {
    int flat = tid + it * 256; int v = flat >> 4, sb = flat & 15;
    *(us8*)&VT[v][sb * 8] = *(const us8*)&VTg[((size_t)bh * 64 + v) * T_SEQ + c * CH + sb * 8];
  }
  __syncthreads();

  {  // Gram (f32, exact)
    int i = tid >> 4, j = tid & 15;
    float m = 0.f;
    for (int cc = 0; cc < CH; ++cc) m += XKT[i][cc] * XKT[j][cc];
    Mk[((size_t)bh * NCHUNK + c) * 256 + tid] = m;
  }

  f32x4 acc[4][4];
#pragma unroll
  for (int m = 0; m < 4; ++m)
#pragma unroll
    for (int n = 0; n < 4; ++n) acc[m][n] = (f32x4){0.f, 0.f, 0.f, 0.f};

#pragma unroll
  for (int kt = 0; kt < 4; ++kt) {
    const int s0 = kt * 32 + lg * 8;
    bf16x8 bfr[4];
#pragma unroll
    for (int nt = 0; nt < 4; ++nt) bfr[nt] = *(const bf16x8*)&VT[nt * 16 + ln][s0];
#pragma unroll
    for (int mi = 0; mi < 4; ++mi) {
      const int iidx = wid * 4 + mi;
      float4 xi0 = *(const float4*)&XKT[iidx][s0];
      float4 xi1 = *(const float4*)&XKT[iidx][s0 + 4];
      float4 xj0 = *(const float4*)&XKT[ln][s0];
      float4 xj1 = *(const float4*)&XKT[ln][s0 + 4];
      bf16x8 afr;
      afr[0] = (short)f2b(xi0.x * xj0.x); afr[1] = (short)f2b(xi0.y * xj0.y);
      afr[2] = (short)f2b(xi0.z * xj0.z); afr[3] = (short)f2b(xi0.w * xj0.w);
      afr[4] = (short)f2b(xi1.x * xj1.x); afr[5] = (short)f2b(xi1.y * xj1.y);
      afr[6] = (short)f2b(xi1.z * xj1.z); afr[7] = (short)f2b(xi1.w * xj1.w);
#pragma unroll
      for (int nt = 0; nt < 4; ++nt)
        acc[mi][nt] = __builtin_amdgcn_mfma_f32_16x16x32_bf16(afr, bfr[nt], acc[mi][nt], 0, 0, 0);
    }
  }

  unsigned short* Sp = Sraw + ((size_t)bh * NCHUNK + c) * (64 * 256);
#pragma unroll
  for (int mi = 0; mi < 4; ++mi) {
    int r0 = (wid * 4 + mi) * 16 + lg * 4;
#pragma unroll
    for (int nt = 0; nt < 4; ++nt) {
      int n = nt * 16 + ln;
      us4 pk;
#pragma unroll
      for (int j = 0; j < 4; ++j) pk[j] = f2b(acc[mi][nt][j]);
      *(us4*)&Sp[(size_t)n * 256 + r0] = pk;
    }
  }
}

// ---------------------------------------------------------------------------
// Phase 2: exclusive prefix over chunks (bf16 in/out, f32 accumulate)
// ---------------------------------------------------------------------------
__global__ __launch_bounds__(256) void k_prefix_s(const unsigned short* __restrict__ Sraw,
                                                  unsigned short* __restrict__ Spre) {
  const int bh = blockIdx.y;
  const int e8 = blockIdx.x * 256 + threadIdx.x;  // < 2048
  size_t base = (size_t)bh * NCHUNK * 16384 + (size_t)e8 * 8;
  float run[8] = {0.f, 0.f, 0.f, 0.f, 0.f, 0.f, 0.f, 0.f};
  for (int cc = 0; cc < NCHUNK; ++cc) {
    us8 v = *(const us8*)&Sraw[base + (size_t)cc * 16384];
    us8 w;
#pragma unroll
    for (int q = 0; q < 8; ++q) w[q] = f2b(run[q]);
    *(us8*)&Spre[base + (size_t)cc * 16384] = w;
#pragma unroll
    for (int q = 0; q < 8; ++q) run[q] += b2f(v[q]);
  }
}

__global__ __launch_bounds__(256) void k_prefix_mk(float* __restrict__ Mk) {
  const int bh = blockIdx.x;
  const int e = threadIdx.x;
  size_t base = (size_t)bh * NCHUNK * 256 + e;
  float run = 0.f;
  for (int c = 0; c < NCHUNK; ++c) {
    float v = Mk[base + (size_t)c * 256];
    Mk[base + (size_t)c * 256] = run;
    run += v;
  }
}

// ---------------------------------------------------------------------------
// Phase 3 (MFMA): att = (XQ XK^T)^2/16 masked; o = att@V + qf@P; z in f32.
// ---------------------------------------------------------------------------
__global__ __launch_bounds__(256) void k_attn_out(const float* __restrict__ QK,
                                                  const unsigned short* __restrict__ VTg,
                                                  const float* __restrict__ gamma,
                                                  const float* __restrict__ beta,
                                                  const unsigned short* __restrict__ Spre,
                                                  const float* __restrict__ Mkp,
                                                  unsigned short* __restrict__ OAB) {
  const int c = blockIdx.x, bh = blockIdx.y;
  const int b = bh >> 4, h = bh & 15;
  __shared__ unsigned short XQb[128][40];   // bf16, cols 16..31 zero
  __shared__ unsigned short XKb[128][40];
  __shared__ unsigned short attb[128 * 128];  // swizzled: idx = t*128 + (s ^ ((t&7)<<3))
  __shared__ unsigned short VT[64][152];
  __shared__ float mksh[256];
  const int tid = threadIdx.x;
  const int lane = tid & 63, wid = tid >> 6;
  const int ln = lane & 15, lg = lane >> 4;

  {
    int r = tid & 127;
    const float* src = QK + (size_t)(b * T_SEQ + c * CH + r) * 512 + (tid < 128 ? 0 : 256) + h * FDIM;
    unsigned short* dst = (tid < 128) ? &XQb[r][0] : &XKb[r][0];
    float xr[16];
    ln16(src, gamma, beta, xr);
    us8 lo, hi, z8;
#pragma unroll
    for (int q = 0; q < 8; ++q) { lo[q] = f2b(xr[q]); hi[q] = f2b(xr[8 + q]); z8[q] = 0; }
    *(us8*)&dst[0] = lo; *(us8*)&dst[8] = hi;
    *(us8*)&dst[16] = z8; *(us8*)&dst[24] = z8;
  }
#pragma unroll
  for (int it = 0; it < 4; ++it) {
    int flat = tid + it * 256; int v = flat >> 4, sb = flat & 15;
    *(us8*)&VT[v][sb * 8] = *(const us8*)&VTg[((size_t)bh * 64 + v) * T_SEQ + c * CH + sb * 8];
  }
  mksh[tid] = Mkp[((size_t)bh * NCHUNK + c) * 256 + tid];
  __syncthreads();

  const int tb = wid * 32;  // this wave's t-rows [tb, tb+32)
  const f32x4 zero4 = {0.f, 0.f, 0.f, 0.f};

  // --- att phase (K=16 padded to 32) ---
  bf16x8 aq0 = *(const bf16x8*)&XQb[tb + ln][lg * 8];
  bf16x8 aq1 = *(const bf16x8*)&XQb[tb + 16 + ln][lg * 8];
  float zin[2][4];
#pragma unroll
  for (int mt = 0; mt < 2; ++mt)
#pragma unroll
    for (int j = 0; j < 4; ++j) zin[mt][j] = 0.f;

#pragma unroll
  for (int nt = 0; nt < 8; ++nt) {
    bf16x8 bk = *(const bf16x8*)&XKb[nt * 16 + ln][lg * 8];
    f32x4 c0 = __builtin_amdgcn_mfma_f32_16x16x32_bf16(aq0, bk, zero4, 0, 0, 0);
    f32x4 c1 = __builtin_amdgcn_mfma_f32_16x16x32_bf16(aq1, bk, zero4, 0, 0, 0);
    int s = nt * 16 + ln;
#pragma unroll
    for (int j = 0; j < 4; ++j) {
      int t0 = tb + lg * 4 + j;
      float d0 = c0[j];
      float a0 = (s <= t0) ? d0 * d0 * 0.0625f : 0.f;
      zin[0][j] += a0;
      attb[t0 * 128 + (s ^ ((t0 & 7) << 3))] = f2b(a0);
      int t1 = t0 + 16;
      float d1 = c1[j];
      float a1 = (s <= t1) ? d1 * d1 * 0.0625f : 0.f;
      zin[1][j] += a1;
      attb[t1 * 128 + (s ^ ((t1 & 7) << 3))] = f2b(a1);
    }
  }
#pragma unroll
  for (int mt = 0; mt < 2; ++mt)
#pragma unroll
    for (int j = 0; j < 4; ++j) {
      float zz = zin[mt][j];
      zz += __shfl_xor(zz, 1, 64);
      zz += __shfl_xor(zz, 2, 64);
      zz += __shfl_xor(zz, 4, 64);
      zz += __shfl_xor(zz, 8, 64);
      zin[mt][j] = zz;
    }

  // --- PV intra (K=128 over att) ---
  f32x4 o[2][4];
#pragma unroll
  for (int mt = 0; mt < 2; ++mt)
#pragma unroll
    for (int nt = 0; nt < 4; ++nt) o[mt][nt] = zero4;

#pragma unroll
  for (int kt = 0; kt < 4; ++kt) {
    int s0 = kt * 32 + lg * 8;
    bf16x8 a0 = *(const bf16x8*)&attb[(tb + ln) * 128 + (s0 ^ ((ln & 7) << 3))];
    bf16x8 a1 = *(const bf16x8*)&attb[(tb + 16 + ln) * 128 + (s0 ^ ((ln & 7) << 3))];
#pragma unroll
    for (int nt = 0; nt < 4; ++nt) {
      bf16x8 bv = *(const bf16x8*)&VT[nt * 16 + ln][s0];
      o[0][nt] = __builtin_amdgcn_mfma_f32_16x16x32_bf16(a0, bv, o[0][nt], 0, 0, 0);
      o[1][nt] = __builtin_amdgcn_mfma_f32_16x16x32_bf16(a1, bv, o[1][nt], 0, 0, 0);
    }
  }

  // --- inter (K=256 over qf, B from global prefix state) ---
  const unsigned short* Sp = Spre + ((size_t)bh * NCHUNK + c) * (64 * 256);
  bf16x8 xlo0 = *(const bf16x8*)&XQb[tb + ln][0];
  bf16x8 xhi0 = *(const bf16x8*)&XQb[tb + ln][8];
  bf16x8 xlo1 = *(const bf16x8*)&XQb[tb + 16 + ln][0];
  bf16x8 xhi1 = *(const bf16x8*)&XQb[tb + 16 + ln][8];
#pragma unroll
  for (int kt = 0; kt < 8; ++kt) {
    int i = kt * 2 + (lg >> 1);
    float xqi0 = b2f(XQb[tb + ln][i]) * 0.0625f;
    float xqi1 = b2f(XQb[tb + 16 + ln][i]) * 0.0625f;
    bf16x8 sel0 = (lg & 1) ? xhi0 : xlo0;
    bf16x8 sel1 = (lg & 1) ? xhi1 : xlo1;
    bf16x8 qa0, qa1;
#pragma unroll
    for (int jj = 0; jj < 8; ++jj) {
      qa0[jj] = (short)f2b(xqi0 * b2f((unsigned short)sel0[jj]));
      qa1[jj] = (short)f2b(xqi1 * b2f((unsigned short)sel1[jj]));
    }
    int r0 = kt * 32 + lg * 8;
#pragma unroll
    for (int nt = 0; nt < 4; ++nt) {
      bf16x8 bp = *(const bf16x8*)&Sp[(size_t)(nt * 16 + ln) * 256 + r0];
      o[0][nt] = __builtin_amdgcn_mfma_f32_16x16x32_bf16(qa0, bp, o[0][nt], 0, 0, 0);
      o[1][nt] = __builtin_amdgcn_mfma_f32_16x16x32_bf16(qa1, bp, o[1][nt], 0, 0, 0);
    }
  }

  // --- z_inter (f32, lane-distributed over i=ln; Mk symmetric) ---
  float zi2[2][4];
#pragma unroll
  for (int mt = 0; mt < 2; ++mt)
#pragma unroll
    for (int j = 0; j < 4; ++j) {
      int t = tb + mt * 16 + lg * 4 + j;
      float xqi = b2f(XQb[t][ln]);
      float p = 0.f;
#pragma unroll
      for (int jm = 0; jm < 16; ++jm) p += b2f(XQb[t][jm]) * mksh[jm * 16 + ln];
      p *= xqi;
      p += __shfl_xor(p, 1, 64);
      p += __shfl_xor(p, 2, 64);
      p += __shfl_xor(p, 4, 64);
      p += __shfl_xor(p, 8, 64);
      zi2[mt][j] = p * 0.0625f;
    }

  // --- epilogue ---
  unsigned short* ob = OAB + ((size_t)(b * T_SEQ + c * CH)) * 1024 + h * 64;
#pragma unroll
  for (int mt = 0; mt < 2; ++mt)
#pragma unroll
    for (int j = 0; j < 4; ++j) {
      int t = tb + mt * 16 + lg * 4 + j;
      float inv = 1.0f / (zin[mt][j] + zi2[mt][j] + 1e-10f);
#pragma unroll
      for (int nt = 0; nt < 4; ++nt)
        ob[(size_t)t * 1024 + nt * 16 + ln] = f2b(o[mt][nt][j] * inv);
    }
}

// ---------------------------------------------------------------------------
extern "C" void kernel_launch(void* const* d_in, const int* in_sizes, int n_in,
                              void* d_out, int out_size, void* d_ws, size_t ws_size,
                              hipStream_t stream) {
  const float* hs    = (const float*)d_in[0];
  const float* Wq    = (const float*)d_in[1];
  const float* Wk    = (const float*)d_in[2];
  const float* Wv    = (const float*)d_in[3];
  const float* Wo    = (const float*)d_in[4];
  const float* gamma = (const float*)d_in[5];
  const float* beta  = (const float*)d_in[6];
  float* out = (float*)d_out;
  float* ws  = (float*)d_ws;

  float* QK = ws + QK_OFF;
  unsigned short* VTg  = (unsigned short*)(ws + VT_OFF);
  unsigned short* Sraw = (unsigned short*)(ws + SRAW_OFF);
  unsigned short* Spre = (unsigned short*)(ws + SPRE_OFF);
  float* Mk = ws + MK_OFF;
  unsigned short* HSB  = (unsigned short*)(ws + HSB_OFF);
  unsigned short* OAB  = (unsigned short*)(ws + OAB_OFF);
  unsigned short* WQKB = (unsigned short*)(ws + WQK_OFF);
  unsigned short* WVB  = (unsigned short*)(ws + WV_OFF);
  unsigned short* WOB  = (unsigned short*)(ws + WO_OFF);

  dim3 blk(256);
  f32_to_bf16<<<4096, blk, 0, stream>>>(hs, HSB, TOK * HIDDEN / 8);
  f32_to_bf16<<<128, blk, 0, stream>>>(Wq, WQKB, 256 * HIDDEN / 8);
  f32_to_bf16<<<128, blk, 0, stream>>>(Wk, WQKB + 256 * HIDDEN, 256 * HIDDEN / 8);
  f32_to_bf16<<<512, blk, 0, stream>>>(Wv, WVB, 1024 * HIDDEN / 8);
  f32_to_bf16<<<512, blk, 0, stream>>>(Wo, WOB, 1024 * HIDDEN / 8);

  gemm_mfma<0><<<dim3(64, 4), blk, 0, stream>>>(HSB, WQKB, QK, 512, HIDDEN);
  gemm_mfma<2><<<dim3(64, 8), blk, 0, stream>>>(HSB, WVB, VTg, 1024, HIDDEN);

  k_states<<<dim3(NCHUNK, NBH), blk, 0, stream>>>(QK, VTg, gamma, beta, Sraw, Mk);
  k_prefix_s<<<dim3(8, NBH), blk, 0, stream>>>(Sraw, Spre);
  k_prefix_mk<<<NBH, blk, 0, stream>>>(Mk);
  k_attn_out<<<dim3(NCHUNK, NBH), blk, 0, stream>>>(QK, VTg, gamma, beta, Spre, Mk, OAB);

  gemm_mfma<0><<<dim3(64, 8), blk, 0, stream>>>(OAB, WOB, out, 1024, HIDDEN);
}